// Round 13
// baseline (223.050 us; speedup 1.0000x reference)
//
#include <hip/hip_runtime.h>
#include <hip/hip_fp16.h>
#include <stdint.h>
#include <string.h>

// LightGCN propagation — R12 skeleton + expand-in-K1 + pruned ELL + slot L3.
//  k0: mark sampled nodes into mask3 AND mask2 (tiny).
//  K1: wide-block LDS-staged counting sort + inline mask expand
//      (mask2 |= cols of rows in mask3) + cvt ride-along.
//  s1: per-bucket ELL build in LDS -> pruned writeout (mask2 rows only)
//      -> layer-1 spmm from LDS; acc0 ride-along.
//  spmm2: global ELL (mask2 rows), fp16 gathers + acc1 ride-along.
//  sp3: slot-form layer 3 — 8192 sample slots, e2+e3 folded into acc_small.
//  dot: batched dot on acc_small only.

#define NUM_USERS 100000
#define NUM_ITEMS 50000
#define N_NODES   150000
#define DIM       64
#define N_EDGES   1200000
#define ND        (N_NODES * DIM)
#define NB        4096
#define NSAMP     (2 * NB)

#define ELL_W     24
#define NBKT      640               // buckets
#define RPB       235               // rows per bucket (640*235 = 150400)
#define NROWS_PAD (NBKT * RPB)
#define BCAP      2176              // records per bucket array (mean 1875, +7s)
#define SCAP      11                // K1 LDS staging records per bucket
#define OVF_CAP   512

#define K1_THREADS     1024
#define K1_EDGE_BLOCKS 256
#define K1_ROUNDS      2
#define K1_CVT_BLOCKS  128

#define S1_ACC_BLOCKS  512          // 16 slots/block
#define SPMM_BLOCKS    9375         // 16 rows/block
#define ACC_BLOCKS     512          // 16 slots/block
#define SP3_BLOCKS     512          // 16 slots/block over 8192 slots

// ---- fp16 pack/unpack helpers (compute in fp32) ---------------------------
__device__ __forceinline__ int h2i(__half2 h) { int r; memcpy(&r, &h, 4); return r; }
__device__ __forceinline__ __half2 i2h(int i) { __half2 h; memcpy(&h, &i, 4); return h; }

__device__ __forceinline__ float4 loadh4(const __half* p) {
    int2 v = *(const int2*)p;
    float2 a = __half22float2(i2h(v.x));
    float2 b = __half22float2(i2h(v.y));
    return make_float4(a.x, a.y, b.x, b.y);
}
__device__ __forceinline__ void storeh4(__half* p, float4 v) {
    int2 o;
    o.x = h2i(__floats2half2_rn(v.x, v.y));
    o.y = h2i(__floats2half2_rn(v.z, v.w));
    *(int2*)p = o;
}
__device__ __forceinline__ float4 f4fma(float v, float4 x, float4 a) {
    a.x += v * x.x; a.y += v * x.y; a.z += v * x.z; a.w += v * x.w;
    return a;
}

// ---------------------------------------------------------------------------
// k0: mark sampled nodes in mask3 and mask2
// ---------------------------------------------------------------------------
__global__ void k0_kernel(const int* __restrict__ users,
                          const int* __restrict__ items,
                          unsigned char* __restrict__ mask3,
                          unsigned char* __restrict__ mask2) {
    int i = blockIdx.x * blockDim.x + threadIdx.x;
    int n = -1;
    if (i < NB)          n = users[i];
    else if (i < NSAMP)  n = NUM_USERS + items[i - NB];
    if (n >= 0) { mask3[n] = 1; mask2[n] = 1; }
}

// ---------------------------------------------------------------------------
// K1: LDS-staged counting sort + inline mask expand + cvt ride-along
// ---------------------------------------------------------------------------
__global__ __launch_bounds__(K1_THREADS)
void k1_kernel(const int* __restrict__ erow,
               const int* __restrict__ ecol,
               const float* __restrict__ evalv,
               const float* __restrict__ ue,
               const float* __restrict__ ie,
               int* __restrict__ gtails,
               int2* __restrict__ barr,
               int4* __restrict__ ovf,
               int* __restrict__ ovf_cnt,
               const unsigned char* __restrict__ mask3,
               unsigned char* __restrict__ mask2,
               __half* __restrict__ xh) {
    __shared__ int2 stage[NBKT * SCAP];   // 56.3 KB
    __shared__ int  scnt[NBKT];           // 2.5 KB
    if (blockIdx.x < K1_EDGE_BLOCKS) {
        for (int k = threadIdx.x; k < NBKT; k += K1_THREADS) scnt[k] = 0;
        __syncthreads();
        for (int rnd = 0; rnd < K1_ROUNDS; ++rnd) {
            int base = ((rnd * K1_EDGE_BLOCKS + (int)blockIdx.x) * K1_THREADS
                        + (int)threadIdx.x) * 4;
            if (base < N_EDGES) {
                int4   r4 = *(const int4*)(erow + base);
                int4   c4 = *(const int4*)(ecol + base);
                float4 v4 = *(const float4*)(evalv + base);
                int   rr[4] = {r4.x, r4.y, r4.z, r4.w};
                int   cc[4] = {c4.x, c4.y, c4.z, c4.w};
                float vv[4] = {v4.x, v4.y, v4.z, v4.w};
                #pragma unroll
                for (int u = 0; u < 4; ++u) {
                    // inline frontier expand (mask3 complete from k0)
                    if (mask3[rr[u]]) mask2[cc[u]] = 1;
                    int b    = rr[u] / RPB;
                    int rloc = rr[u] - b * RPB;
                    int2 rec = make_int2(cc[u] | (rloc << 18), __float_as_int(vv[u]));
                    int s = atomicAdd(&scnt[b], 1);
                    if (s < SCAP) {
                        stage[b * SCAP + s] = rec;
                    } else {
                        atomicSub(&scnt[b], 1);
                        int gp = atomicAdd(&gtails[b], 1);
                        if (gp < BCAP) barr[(size_t)b * BCAP + gp] = rec;
                        else { int q = atomicAdd(ovf_cnt, 1);
                               if (q < OVF_CAP)
                                   ovf[q] = make_int4(rr[u], cc[u], __float_as_int(vv[u]), 0); }
                    }
                }
            }
            __syncthreads();
            for (int b = threadIdx.x; b < NBKT; b += K1_THREADS) {
                int c = scnt[b];
                if (c >= 8) {
                    int gp = atomicAdd(&gtails[b], 8);
                    if (gp + 8 <= BCAP) {
                        int2* dst = barr + (size_t)b * BCAP + gp;
                        #pragma unroll
                        for (int i = 0; i < 8; ++i) dst[i] = stage[b * SCAP + i];
                    } else {
                        for (int i = 0; i < 8; ++i) {
                            int2 rc = stage[b * SCAP + i];
                            if (gp + i < BCAP) barr[(size_t)b * BCAP + gp + i] = rc;
                            else { int q = atomicAdd(ovf_cnt, 1);
                                   if (q < OVF_CAP)
                                       ovf[q] = make_int4(b * RPB + (rc.x >> 18),
                                                          rc.x & 0x3FFFF, rc.y, 0); }
                        }
                    }
                    c -= 8;
                    for (int i = 0; i < c; ++i)
                        stage[b * SCAP + i] = stage[b * SCAP + 8 + i];
                    scnt[b] = c;
                }
            }
            __syncthreads();
        }
        for (int b = threadIdx.x; b < NBKT; b += K1_THREADS) {
            int c = scnt[b];
            if (c > 0) {
                int gp = atomicAdd(&gtails[b], c);
                for (int i = 0; i < c; ++i) {
                    int2 rc = stage[b * SCAP + i];
                    if (gp + i < BCAP) barr[(size_t)b * BCAP + gp + i] = rc;
                    else { int q = atomicAdd(ovf_cnt, 1);
                           if (q < OVF_CAP)
                               ovf[q] = make_int4(b * RPB + (rc.x >> 18),
                                                  rc.x & 0x3FFFF, rc.y, 0); }
                }
            }
        }
    } else {
        // cvt: concat(ue, ie) fp32 -> xh fp16
        const int n4  = ND / 4;
        const int nu4 = NUM_USERS * DIM / 4;
        int i = ((int)blockIdx.x - K1_EDGE_BLOCKS) * K1_THREADS + (int)threadIdx.x;
        const int stride = K1_CVT_BLOCKS * K1_THREADS;
        int2* xh4 = (int2*)xh;
        for (; i < n4; i += stride) {
            float4 v = (i < nu4) ? ((const float4*)ue)[i]
                                 : ((const float4*)ie)[i - nu4];
            int2 o;
            o.x = h2i(__floats2half2_rn(v.x, v.y));
            o.y = h2i(__floats2half2_rn(v.z, v.w));
            xh4[i] = o;
        }
    }
}

// ---------------------------------------------------------------------------
// s1: fused ELL build (LDS) + pruned writeout + layer-1 spmm from LDS
//     + acc0(store) ride-along
// ---------------------------------------------------------------------------
__global__ __launch_bounds__(256)
void s1_kernel(const int* __restrict__ gtails,
               const int2* __restrict__ barr,
               const __half* __restrict__ xh,
               const float* __restrict__ ue,
               const float* __restrict__ ie,
               int* __restrict__ counts,
               int2* __restrict__ ell,
               int4* __restrict__ ovf,
               int* __restrict__ ovf_cnt,
               const unsigned char* __restrict__ mask2,
               const int* __restrict__ users,
               const int* __restrict__ items,
               float* __restrict__ acc_small,
               __half* __restrict__ emb_out) {
    __shared__ __align__(16) int2 lell[RPB * ELL_W];   // 45.1 KB
    __shared__ int lcnt[RPB];
    const int wid  = threadIdx.x >> 6;
    const int lane = threadIdx.x & 63;
    const int g    = lane >> 4;
    const int t    = lane & 15;

    if (blockIdx.x < NBKT) {
        const int bkt   = blockIdx.x;
        const int rbase = bkt * RPB;
        // ---- phase 1: build LDS ELL from sorted records ----
        for (int k = threadIdx.x; k < RPB; k += 256) lcnt[k] = 0;
        __syncthreads();
        int n = gtails[bkt];
        n = n < BCAP ? n : BCAP;
        for (int e = threadIdx.x; e < n; e += 256) {
            int2 rec = barr[(size_t)bkt * BCAP + e];
            int col  = rec.x & 0x3FFFF;
            int rloc = rec.x >> 18;
            int slot = atomicAdd(&lcnt[rloc], 1);
            if (slot < ELL_W)
                lell[rloc * ELL_W + slot] = make_int2(col, rec.y);
            else { int q = atomicAdd(ovf_cnt, 1);
                   if (q < OVF_CAP) ovf[q] = make_int4(rbase + rloc, col, rec.y, 0); }
        }
        __syncthreads();
        // ---- phase 2: pruned writeout — only mask2 rows (used by L2/L3) ----
        {
            int4* g4 = (int4*)(ell + (size_t)rbase * ELL_W);
            const int4* l4 = (const int4*)lell;
            for (int idx = threadIdx.x; idx < RPB * (ELL_W / 2); idx += 256) {
                int row = idx / (ELL_W / 2);
                if (rbase + row < N_NODES && mask2[rbase + row]) g4[idx] = l4[idx];
            }
            for (int k = threadIdx.x; k < RPB; k += 256)
                if (rbase + k < N_NODES && mask2[rbase + k])
                    counts[rbase + k] = lcnt[k];
        }
        // ---- phase 3: layer-1 spmm reading ELL from LDS ----
        int novf = *ovf_cnt;
        novf = novf < OVF_CAP ? novf : OVF_CAP;
        for (int k = 0; k < 15; ++k) {
            int rloc = wid * 4 + g + 16 * k;
            if (rloc >= RPB) break;
            int row = rbase + rloc;
            if (row >= N_NODES) continue;
            int cnt = lcnt[rloc];
            cnt = cnt < ELL_W ? cnt : ELL_W;
            const int2* ep = &lell[rloc * ELL_W];
            float4 a0 = {0,0,0,0}, a1 = {0,0,0,0}, a2 = {0,0,0,0}, a3 = {0,0,0,0};
            int j = 0;
            for (; j + 4 <= cnt; j += 4) {
                int4 cv0 = *(const int4*)(ep + j);
                int4 cv1 = *(const int4*)(ep + j + 2);
                float4 x0 = loadh4(xh + (size_t)cv0.x * DIM + t * 4);
                float4 x1 = loadh4(xh + (size_t)cv0.z * DIM + t * 4);
                float4 x2 = loadh4(xh + (size_t)cv1.x * DIM + t * 4);
                float4 x3 = loadh4(xh + (size_t)cv1.z * DIM + t * 4);
                a0 = f4fma(__int_as_float(cv0.y), x0, a0);
                a1 = f4fma(__int_as_float(cv0.w), x1, a1);
                a2 = f4fma(__int_as_float(cv1.y), x2, a2);
                a3 = f4fma(__int_as_float(cv1.w), x3, a3);
            }
            for (; j + 2 <= cnt; j += 2) {
                int4 cv = *(const int4*)(ep + j);
                float4 x0 = loadh4(xh + (size_t)cv.x * DIM + t * 4);
                float4 x1 = loadh4(xh + (size_t)cv.z * DIM + t * 4);
                a0 = f4fma(__int_as_float(cv.y), x0, a0);
                a1 = f4fma(__int_as_float(cv.w), x1, a1);
            }
            if (j < cnt) {
                int2 cv = ep[j];
                float4 xv = loadh4(xh + (size_t)cv.x * DIM + t * 4);
                a0 = f4fma(__int_as_float(cv.y), xv, a0);
            }
            for (int q = 0; q < novf; ++q) {
                int4 o = ovf[q];
                if (o.x == row) {
                    float4 xv = loadh4(xh + (size_t)o.y * DIM + t * 4);
                    a0 = f4fma(__int_as_float(o.z), xv, a0);
                }
            }
            float4 self = loadh4(xh + (size_t)row * DIM + t * 4);
            float4 r;
            r.x = 0.2f * self.x + 0.8f * ((a0.x + a1.x) + (a2.x + a3.x));
            r.y = 0.2f * self.y + 0.8f * ((a0.y + a1.y) + (a2.y + a3.y));
            r.z = 0.2f * self.z + 0.8f * ((a0.z + a1.z) + (a2.z + a3.z));
            r.w = 0.2f * self.w + 0.8f * ((a0.w + a1.w) + (a2.w + a3.w));
            storeh4(emb_out + (size_t)row * DIM + t * 4, r);
        }
    } else {
        // acc0: store layer-0 contribution from the fp32 tables
        const int s = ((int)blockIdx.x - NBKT) * 16 + wid * 4 + g;   // < 8192
        const int node = (s < NB) ? users[s] : (NUM_USERS + items[s - NB]);
        const float* p = (node < NUM_USERS) ? ue + (size_t)node * DIM
                                            : ie + (size_t)(node - NUM_USERS) * DIM;
        *(float4*)(acc_small + (size_t)s * DIM + t * 4) = *(const float4*)(p + t * 4);
    }
}

// ---------------------------------------------------------------------------
// spmm2 (layer 2): global ELL, masked, fp16 gathers + acc1 ride-along
// ---------------------------------------------------------------------------
__global__ void spmm_kernel(const int* __restrict__ counts,
                            const int2* __restrict__ ell,
                            const __half* __restrict__ xsrc,
                            const unsigned char* __restrict__ mask,
                            const int* __restrict__ ovf_cnt,
                            const int4* __restrict__ ovf,
                            const int* __restrict__ users,
                            const int* __restrict__ items,
                            float* __restrict__ acc_small,
                            __half* __restrict__ xout) {
    const int wid  = threadIdx.x >> 6;
    const int lane = threadIdx.x & 63;
    const int g    = lane >> 4;
    const int t    = lane & 15;

    if (blockIdx.x < SPMM_BLOCKS) {
        const int row = blockIdx.x * 16 + wid * 4 + g;
        bool active = mask[row] != 0;
        int cnt = 0;
        if (active) {
            cnt = counts[row];
            cnt = cnt < ELL_W ? cnt : ELL_W;
        }
        const int2* ep = ell + (size_t)row * ELL_W;
        float4 a0 = {0,0,0,0}, a1 = {0,0,0,0}, a2 = {0,0,0,0}, a3 = {0,0,0,0};
        int j = 0;
        for (; j + 4 <= cnt; j += 4) {
            int4 cv0 = *(const int4*)(ep + j);
            int4 cv1 = *(const int4*)(ep + j + 2);
            float4 x0 = loadh4(xsrc + (size_t)cv0.x * DIM + t * 4);
            float4 x1 = loadh4(xsrc + (size_t)cv0.z * DIM + t * 4);
            float4 x2 = loadh4(xsrc + (size_t)cv1.x * DIM + t * 4);
            float4 x3 = loadh4(xsrc + (size_t)cv1.z * DIM + t * 4);
            a0 = f4fma(__int_as_float(cv0.y), x0, a0);
            a1 = f4fma(__int_as_float(cv0.w), x1, a1);
            a2 = f4fma(__int_as_float(cv1.y), x2, a2);
            a3 = f4fma(__int_as_float(cv1.w), x3, a3);
        }
        for (; j + 2 <= cnt; j += 2) {
            int4 cv = *(const int4*)(ep + j);
            float4 x0 = loadh4(xsrc + (size_t)cv.x * DIM + t * 4);
            float4 x1 = loadh4(xsrc + (size_t)cv.z * DIM + t * 4);
            a0 = f4fma(__int_as_float(cv.y), x0, a0);
            a1 = f4fma(__int_as_float(cv.w), x1, a1);
        }
        if (j < cnt) {
            int2 cv = ep[j];
            float4 xv = loadh4(xsrc + (size_t)cv.x * DIM + t * 4);
            a0 = f4fma(__int_as_float(cv.y), xv, a0);
        }
        int novf = *ovf_cnt;
        if (novf > 0) {
            novf = novf < OVF_CAP ? novf : OVF_CAP;
            for (int k = 0; k < novf; ++k) {
                int4 o = ovf[k];
                if (active && o.x == row) {
                    float4 xv = loadh4(xsrc + (size_t)o.y * DIM + t * 4);
                    a0 = f4fma(__int_as_float(o.z), xv, a0);
                }
            }
        }
        if (active) {
            float4 self = loadh4(xsrc + (size_t)row * DIM + t * 4);
            float4 r;
            r.x = 0.2f * self.x + 0.8f * ((a0.x + a1.x) + (a2.x + a3.x));
            r.y = 0.2f * self.y + 0.8f * ((a0.y + a1.y) + (a2.y + a3.y));
            r.z = 0.2f * self.z + 0.8f * ((a0.z + a1.z) + (a2.z + a3.z));
            r.w = 0.2f * self.w + 0.8f * ((a0.w + a1.w) + (a2.w + a3.w));
            storeh4(xout + (size_t)row * DIM + t * 4, r);
        }
    } else {
        // acc1 += e1 at sampled slots (xsrc = emb_a)
        const int s = (blockIdx.x - SPMM_BLOCKS) * 16 + wid * 4 + g;
        const int node = (s < NB) ? users[s] : (NUM_USERS + items[s - NB]);
        float4 v = loadh4(xsrc + (size_t)node * DIM + t * 4);
        float4* ap = (float4*)(acc_small + (size_t)s * DIM + t * 4);
        float4 a = *ap;
        a.x += v.x; a.y += v.y; a.z += v.z; a.w += v.w;
        *ap = a;
    }
}

// ---------------------------------------------------------------------------
// sp3: slot-form layer 3 — acc[slot] += e2(node) + e3(node)
//      e3 = 0.2*self + 0.8*sum, self = e2(node) from emb_b
// ---------------------------------------------------------------------------
__global__ void sp3_kernel(const int* __restrict__ counts,
                           const int2* __restrict__ ell,
                           const __half* __restrict__ emb2,
                           const int* __restrict__ ovf_cnt,
                           const int4* __restrict__ ovf,
                           const int* __restrict__ users,
                           const int* __restrict__ items,
                           float* __restrict__ acc_small) {
    const int wid  = threadIdx.x >> 6;
    const int lane = threadIdx.x & 63;
    const int g    = lane >> 4;
    const int t    = lane & 15;
    const int s = blockIdx.x * 16 + wid * 4 + g;          // < 8192
    if (s >= NSAMP) return;
    const int node = (s < NB) ? users[s] : (NUM_USERS + items[s - NB]);

    int cnt = counts[node];
    cnt = cnt < ELL_W ? cnt : ELL_W;
    const int2* ep = ell + (size_t)node * ELL_W;
    float4 a0 = {0,0,0,0}, a1 = {0,0,0,0}, a2 = {0,0,0,0}, a3 = {0,0,0,0};
    int j = 0;
    for (; j + 4 <= cnt; j += 4) {
        int4 cv0 = *(const int4*)(ep + j);
        int4 cv1 = *(const int4*)(ep + j + 2);
        float4 x0 = loadh4(emb2 + (size_t)cv0.x * DIM + t * 4);
        float4 x1 = loadh4(emb2 + (size_t)cv0.z * DIM + t * 4);
        float4 x2 = loadh4(emb2 + (size_t)cv1.x * DIM + t * 4);
        float4 x3 = loadh4(emb2 + (size_t)cv1.z * DIM + t * 4);
        a0 = f4fma(__int_as_float(cv0.y), x0, a0);
        a1 = f4fma(__int_as_float(cv0.w), x1, a1);
        a2 = f4fma(__int_as_float(cv1.y), x2, a2);
        a3 = f4fma(__int_as_float(cv1.w), x3, a3);
    }
    for (; j + 2 <= cnt; j += 2) {
        int4 cv = *(const int4*)(ep + j);
        float4 x0 = loadh4(emb2 + (size_t)cv.x * DIM + t * 4);
        float4 x1 = loadh4(emb2 + (size_t)cv.z * DIM + t * 4);
        a0 = f4fma(__int_as_float(cv.y), x0, a0);
        a1 = f4fma(__int_as_float(cv.w), x1, a1);
    }
    if (j < cnt) {
        int2 cv = ep[j];
        float4 xv = loadh4(emb2 + (size_t)cv.x * DIM + t * 4);
        a0 = f4fma(__int_as_float(cv.y), xv, a0);
    }
    int novf = *ovf_cnt;
    if (novf > 0) {
        novf = novf < OVF_CAP ? novf : OVF_CAP;
        for (int k = 0; k < novf; ++k) {
            int4 o = ovf[k];
            if (o.x == node) {
                float4 xv = loadh4(emb2 + (size_t)o.y * DIM + t * 4);
                a0 = f4fma(__int_as_float(o.z), xv, a0);
            }
        }
    }
    float4 self = loadh4(emb2 + (size_t)node * DIM + t * 4);
    float4* ap = (float4*)(acc_small + (size_t)s * DIM + t * 4);
    float4 a = *ap;
    // += e2 + e3 = self + (0.2*self + 0.8*sum) = 1.2*self + 0.8*sum
    a.x += 1.2f * self.x + 0.8f * ((a0.x + a1.x) + (a2.x + a3.x));
    a.y += 1.2f * self.y + 0.8f * ((a0.y + a1.y) + (a2.y + a3.y));
    a.z += 1.2f * self.z + 0.8f * ((a0.z + a1.z) + (a2.z + a3.z));
    a.w += 1.2f * self.w + 0.8f * ((a0.w + a1.w) + (a2.w + a3.w));
    *ap = a;
}

// ---------------------------------------------------------------------------
// out[b] = dot(acc[b], acc[NB+b]) / 16
// ---------------------------------------------------------------------------
__global__ void dot_kernel(const float* __restrict__ acc_small,
                           float* __restrict__ out) {
    int w = (blockIdx.x * blockDim.x + threadIdx.x) >> 6;
    int lane = threadIdx.x & 63;
    if (w >= NB) return;
    float p = acc_small[w * DIM + lane] * acc_small[(NB + w) * DIM + lane];
    #pragma unroll
    for (int o = 32; o > 0; o >>= 1) p += __shfl_down(p, o, 64);
    if (lane == 0) out[w] = p * (1.0f / 16.0f);
}

// ---------------------------------------------------------------------------
extern "C" void kernel_launch(void* const* d_in, const int* in_sizes, int n_in,
                              void* d_out, int out_size, void* d_ws, size_t ws_size,
                              hipStream_t stream) {
    const int*   users = (const int*)  d_in[0];
    const int*   items = (const int*)  d_in[1];
    const int*   erow  = (const int*)  d_in[2];
    const int*   ecol  = (const int*)  d_in[3];
    const float* evalv = (const float*)d_in[4];
    const float* ue    = (const float*)d_in[5];
    const float* ie    = (const float*)d_in[6];
    float* out = (float*)d_out;

    // workspace layout (~101 MB)
    __half* xh        = (__half*)d_ws;                      // 19.2 MB
    __half* emb_a     = xh + ND;                            // 19.2 MB
    __half* emb_b     = emb_a + ND;                         // 19.2 MB
    float*  acc_small = (float*)(emb_b + ND);               // 2 MB
    int2*   barr      = (int2*)(acc_small + NSAMP * DIM);   // 11.1 MB
    int2*   ell       = barr + (size_t)NBKT * BCAP;         // 28.9 MB
    int*    counts    = (int*)(ell + (size_t)NROWS_PAD * ELL_W); // 0.6 MB
    int*    gtails    = counts + NROWS_PAD;                 // NBKT
    int*    ovf_cnt   = gtails + NBKT;                      // 1
    int4*   ovf       = (int4*)(((uintptr_t)(ovf_cnt + 1) + 15) & ~(uintptr_t)15);
    unsigned char* mask3 = (unsigned char*)(ovf + OVF_CAP); // N_NODES
    unsigned char* mask2 = mask3 + N_NODES;                 // N_NODES

    // zero gtails | ovf_cnt | ovf | mask3 | mask2 (contiguous, ~310 KB)
    size_t zbytes = (size_t)((mask2 + N_NODES) - (unsigned char*)gtails);
    hipMemsetAsync(gtails, 0, zbytes, stream);

    k0_kernel<<<(NSAMP + 255) / 256, 256, 0, stream>>>(users, items, mask3, mask2);

    k1_kernel<<<K1_EDGE_BLOCKS + K1_CVT_BLOCKS, K1_THREADS, 0, stream>>>(
        erow, ecol, evalv, ue, ie, gtails, barr, ovf, ovf_cnt, mask3, mask2, xh);

    // s1: ELL build + pruned writeout + layer-1 spmm + acc0
    s1_kernel<<<NBKT + S1_ACC_BLOCKS, 256, 0, stream>>>(
        gtails, barr, xh, ue, ie, counts, ell, ovf, ovf_cnt, mask2,
        users, items, acc_small, emb_a);

    // layer 2 (mask2) + acc1 (from emb_a)
    spmm_kernel<<<SPMM_BLOCKS + ACC_BLOCKS, 256, 0, stream>>>(
        counts, ell, emb_a, mask2, ovf_cnt, ovf,
        users, items, acc_small, emb_b);

    // layer 3 slot-form: acc += e2 + e3
    sp3_kernel<<<SP3_BLOCKS, 256, 0, stream>>>(
        counts, ell, emb_b, ovf_cnt, ovf, users, items, acc_small);

    // dot on acc only
    dot_kernel<<<(NB * 64 + 255) / 256, 256, 0, stream>>>(acc_small, out);
}

// Round 14
// 211.714 us; speedup vs baseline: 1.0535x; 1.0535x over previous
//
#include <hip/hip_runtime.h>
#include <hip/hip_fp16.h>
#include <stdint.h>
#include <string.h>

// LightGCN propagation — best-of recombination (R12 skeleton):
//  K1: wide-block LDS-staged counting sort + mark + cvt ride-along (R11 form;
//      NO inline expand — that regressed K1 43->53us in R13).
//  s1: per-bucket ELL build in LDS -> cnt-PRUNED writeout (ceil(cnt/2) int4
//      per row, rows line-aligned; 29->~11MB) -> layer-1 spmm from LDS;
//      acc0 + mask expand + mask copy ride-alongs.
//  spmm2: global ELL (mask2 rows), fp16 gathers + acc1 ride-along.
//  sp3: slot-form layer 3 (R13-proven) — acc += e2 + e3 at 8192 slots.
//  dot: batched dot on acc_small only.

#define NUM_USERS 100000
#define NUM_ITEMS 50000
#define N_NODES   150000
#define DIM       64
#define N_EDGES   1200000
#define ND        (N_NODES * DIM)
#define NB        4096
#define NSAMP     (2 * NB)

#define ELL_W     24
#define NBKT      640               // buckets
#define RPB       235               // rows per bucket (640*235 = 150400)
#define NROWS_PAD (NBKT * RPB)
#define BCAP      2176              // records per bucket array (mean 1875, +7s)
#define SCAP      11                // K1 LDS staging records per bucket
#define OVF_CAP   512

#define K1_THREADS     1024
#define K1_EDGE_BLOCKS 256
#define K1_ROUNDS      2
#define K1_MARK_BLOCKS 8            // 8*1024 = 8192 = NSAMP
#define K1_CVT_BLOCKS  128

#define S1_ACC_BLOCKS  512          // 16 slots/block
#define S1_EXP_BLOCKS  2048
#define S1_CPY_BLOCKS  586

#define SPMM_BLOCKS    9375         // 16 rows/block
#define ACC_BLOCKS     512          // 16 slots/block
#define SP3_BLOCKS     512          // 16 slots/block over 8192 slots

// ---- fp16 pack/unpack helpers (compute in fp32) ---------------------------
__device__ __forceinline__ int h2i(__half2 h) { int r; memcpy(&r, &h, 4); return r; }
__device__ __forceinline__ __half2 i2h(int i) { __half2 h; memcpy(&h, &i, 4); return h; }

__device__ __forceinline__ float4 loadh4(const __half* p) {
    int2 v = *(const int2*)p;
    float2 a = __half22float2(i2h(v.x));
    float2 b = __half22float2(i2h(v.y));
    return make_float4(a.x, a.y, b.x, b.y);
}
__device__ __forceinline__ void storeh4(__half* p, float4 v) {
    int2 o;
    o.x = h2i(__floats2half2_rn(v.x, v.y));
    o.y = h2i(__floats2half2_rn(v.z, v.w));
    *(int2*)p = o;
}
__device__ __forceinline__ float4 f4fma(float v, float4 x, float4 a) {
    a.x += v * x.x; a.y += v * x.y; a.z += v * x.z; a.w += v * x.w;
    return a;
}

// ---------------------------------------------------------------------------
// K1: LDS-staged counting sort (wide blocks) + mark + cvt ride-along [R11]
// ---------------------------------------------------------------------------
__global__ __launch_bounds__(K1_THREADS)
void k1_kernel(const int* __restrict__ erow,
               const int* __restrict__ ecol,
               const float* __restrict__ evalv,
               const int* __restrict__ users,
               const int* __restrict__ items,
               const float* __restrict__ ue,
               const float* __restrict__ ie,
               int* __restrict__ gtails,
               int2* __restrict__ barr,
               int4* __restrict__ ovf,
               int* __restrict__ ovf_cnt,
               unsigned char* __restrict__ mask3,
               __half* __restrict__ xh) {
    __shared__ int2 stage[NBKT * SCAP];   // 56.3 KB
    __shared__ int  scnt[NBKT];           // 2.5 KB
    if (blockIdx.x < K1_EDGE_BLOCKS) {
        for (int k = threadIdx.x; k < NBKT; k += K1_THREADS) scnt[k] = 0;
        __syncthreads();
        for (int rnd = 0; rnd < K1_ROUNDS; ++rnd) {
            int base = ((rnd * K1_EDGE_BLOCKS + (int)blockIdx.x) * K1_THREADS
                        + (int)threadIdx.x) * 4;
            if (base < N_EDGES) {
                int4   r4 = *(const int4*)(erow + base);
                int4   c4 = *(const int4*)(ecol + base);
                float4 v4 = *(const float4*)(evalv + base);
                int   rr[4] = {r4.x, r4.y, r4.z, r4.w};
                int   cc[4] = {c4.x, c4.y, c4.z, c4.w};
                float vv[4] = {v4.x, v4.y, v4.z, v4.w};
                #pragma unroll
                for (int u = 0; u < 4; ++u) {
                    int b    = rr[u] / RPB;
                    int rloc = rr[u] - b * RPB;
                    int2 rec = make_int2(cc[u] | (rloc << 18), __float_as_int(vv[u]));
                    int s = atomicAdd(&scnt[b], 1);
                    if (s < SCAP) {
                        stage[b * SCAP + s] = rec;
                    } else {
                        atomicSub(&scnt[b], 1);
                        int gp = atomicAdd(&gtails[b], 1);
                        if (gp < BCAP) barr[(size_t)b * BCAP + gp] = rec;
                        else { int q = atomicAdd(ovf_cnt, 1);
                               if (q < OVF_CAP)
                                   ovf[q] = make_int4(rr[u], cc[u], __float_as_int(vv[u]), 0); }
                    }
                }
            }
            __syncthreads();
            for (int b = threadIdx.x; b < NBKT; b += K1_THREADS) {
                int c = scnt[b];
                if (c >= 8) {
                    int gp = atomicAdd(&gtails[b], 8);
                    if (gp + 8 <= BCAP) {
                        int2* dst = barr + (size_t)b * BCAP + gp;
                        #pragma unroll
                        for (int i = 0; i < 8; ++i) dst[i] = stage[b * SCAP + i];
                    } else {
                        for (int i = 0; i < 8; ++i) {
                            int2 rc = stage[b * SCAP + i];
                            if (gp + i < BCAP) barr[(size_t)b * BCAP + gp + i] = rc;
                            else { int q = atomicAdd(ovf_cnt, 1);
                                   if (q < OVF_CAP)
                                       ovf[q] = make_int4(b * RPB + (rc.x >> 18),
                                                          rc.x & 0x3FFFF, rc.y, 0); }
                        }
                    }
                    c -= 8;
                    for (int i = 0; i < c; ++i)
                        stage[b * SCAP + i] = stage[b * SCAP + 8 + i];
                    scnt[b] = c;
                }
            }
            __syncthreads();
        }
        for (int b = threadIdx.x; b < NBKT; b += K1_THREADS) {
            int c = scnt[b];
            if (c > 0) {
                int gp = atomicAdd(&gtails[b], c);
                for (int i = 0; i < c; ++i) {
                    int2 rc = stage[b * SCAP + i];
                    if (gp + i < BCAP) barr[(size_t)b * BCAP + gp + i] = rc;
                    else { int q = atomicAdd(ovf_cnt, 1);
                           if (q < OVF_CAP)
                               ovf[q] = make_int4(b * RPB + (rc.x >> 18),
                                                  rc.x & 0x3FFFF, rc.y, 0); }
                }
            }
        }
    } else if (blockIdx.x < K1_EDGE_BLOCKS + K1_MARK_BLOCKS) {
        int i = ((int)blockIdx.x - K1_EDGE_BLOCKS) * K1_THREADS + (int)threadIdx.x;
        if (i < NB)         mask3[users[i]] = 1;
        else if (i < NSAMP) mask3[NUM_USERS + items[i - NB]] = 1;
    } else {
        const int n4  = ND / 4;
        const int nu4 = NUM_USERS * DIM / 4;
        int i = ((int)blockIdx.x - K1_EDGE_BLOCKS - K1_MARK_BLOCKS) * K1_THREADS
                + (int)threadIdx.x;
        const int stride = K1_CVT_BLOCKS * K1_THREADS;
        int2* xh4 = (int2*)xh;
        for (; i < n4; i += stride) {
            float4 v = (i < nu4) ? ((const float4*)ue)[i]
                                 : ((const float4*)ie)[i - nu4];
            int2 o;
            o.x = h2i(__floats2half2_rn(v.x, v.y));
            o.y = h2i(__floats2half2_rn(v.z, v.w));
            xh4[i] = o;
        }
    }
}

// ---------------------------------------------------------------------------
// s1: fused ELL build (LDS) + cnt-pruned writeout + layer-1 spmm from LDS
//     + acc0(store) + mask expand + mask copy ride-alongs
// ---------------------------------------------------------------------------
__global__ __launch_bounds__(256)
void s1_kernel(const int* __restrict__ erow,
               const int* __restrict__ ecol,
               const int* __restrict__ gtails,
               const int2* __restrict__ barr,
               const __half* __restrict__ xh,
               const float* __restrict__ ue,
               const float* __restrict__ ie,
               int* __restrict__ counts,
               int2* __restrict__ ell,
               int4* __restrict__ ovf,
               int* __restrict__ ovf_cnt,
               const unsigned char* __restrict__ mask3,
               unsigned char* __restrict__ mask2,
               const int* __restrict__ users,
               const int* __restrict__ items,
               float* __restrict__ acc_small,
               __half* __restrict__ emb_out) {
    __shared__ __align__(16) int2 lell[RPB * ELL_W];   // 45.1 KB
    __shared__ int lcnt[RPB];
    const int wid  = threadIdx.x >> 6;
    const int lane = threadIdx.x & 63;
    const int g    = lane >> 4;
    const int t    = lane & 15;

    if (blockIdx.x < NBKT) {
        const int bkt   = blockIdx.x;
        const int rbase = bkt * RPB;
        // ---- phase 1: build LDS ELL from sorted records ----
        for (int k = threadIdx.x; k < RPB; k += 256) lcnt[k] = 0;
        __syncthreads();
        int n = gtails[bkt];
        n = n < BCAP ? n : BCAP;
        for (int e = threadIdx.x; e < n; e += 256) {
            int2 rec = barr[(size_t)bkt * BCAP + e];
            int col  = rec.x & 0x3FFFF;
            int rloc = rec.x >> 18;
            int slot = atomicAdd(&lcnt[rloc], 1);
            if (slot < ELL_W)
                lell[rloc * ELL_W + slot] = make_int2(col, rec.y);
            else { int q = atomicAdd(ovf_cnt, 1);
                   if (q < OVF_CAP) ovf[q] = make_int4(rbase + rloc, col, rec.y, 0); }
        }
        __syncthreads();
        // ---- phase 2: cnt-pruned writeout (rows are 192B line-aligned) ----
        {
            int4* g4 = (int4*)(ell + (size_t)rbase * ELL_W);
            const int4* l4 = (const int4*)lell;
            const int PPR = ELL_W / 2;   // 12 int4 pairs per row
            for (int idx = threadIdx.x; idx < RPB * PPR; idx += 256) {
                int row = idx / PPR;
                int pr  = idx - row * PPR;
                int c = lcnt[row]; c = c < ELL_W ? c : ELL_W;
                if (pr * 2 < c) g4[idx] = l4[idx];
            }
            for (int k = threadIdx.x; k < RPB; k += 256) counts[rbase + k] = lcnt[k];
        }
        // ---- phase 3: layer-1 spmm reading ELL from LDS ----
        int novf = *ovf_cnt;
        novf = novf < OVF_CAP ? novf : OVF_CAP;
        for (int k = 0; k < 15; ++k) {
            int rloc = wid * 4 + g + 16 * k;
            if (rloc >= RPB) break;
            int row = rbase + rloc;
            if (row >= N_NODES) continue;
            int cnt = lcnt[rloc];
            cnt = cnt < ELL_W ? cnt : ELL_W;
            const int2* ep = &lell[rloc * ELL_W];
            float4 a0 = {0,0,0,0}, a1 = {0,0,0,0}, a2 = {0,0,0,0}, a3 = {0,0,0,0};
            int j = 0;
            for (; j + 4 <= cnt; j += 4) {
                int4 cv0 = *(const int4*)(ep + j);
                int4 cv1 = *(const int4*)(ep + j + 2);
                float4 x0 = loadh4(xh + (size_t)cv0.x * DIM + t * 4);
                float4 x1 = loadh4(xh + (size_t)cv0.z * DIM + t * 4);
                float4 x2 = loadh4(xh + (size_t)cv1.x * DIM + t * 4);
                float4 x3 = loadh4(xh + (size_t)cv1.z * DIM + t * 4);
                a0 = f4fma(__int_as_float(cv0.y), x0, a0);
                a1 = f4fma(__int_as_float(cv0.w), x1, a1);
                a2 = f4fma(__int_as_float(cv1.y), x2, a2);
                a3 = f4fma(__int_as_float(cv1.w), x3, a3);
            }
            for (; j + 2 <= cnt; j += 2) {
                int4 cv = *(const int4*)(ep + j);
                float4 x0 = loadh4(xh + (size_t)cv.x * DIM + t * 4);
                float4 x1 = loadh4(xh + (size_t)cv.z * DIM + t * 4);
                a0 = f4fma(__int_as_float(cv.y), x0, a0);
                a1 = f4fma(__int_as_float(cv.w), x1, a1);
            }
            if (j < cnt) {
                int2 cv = ep[j];
                float4 xv = loadh4(xh + (size_t)cv.x * DIM + t * 4);
                a0 = f4fma(__int_as_float(cv.y), xv, a0);
            }
            for (int q = 0; q < novf; ++q) {
                int4 o = ovf[q];
                if (o.x == row) {
                    float4 xv = loadh4(xh + (size_t)o.y * DIM + t * 4);
                    a0 = f4fma(__int_as_float(o.z), xv, a0);
                }
            }
            float4 self = loadh4(xh + (size_t)row * DIM + t * 4);
            float4 r;
            r.x = 0.2f * self.x + 0.8f * ((a0.x + a1.x) + (a2.x + a3.x));
            r.y = 0.2f * self.y + 0.8f * ((a0.y + a1.y) + (a2.y + a3.y));
            r.z = 0.2f * self.z + 0.8f * ((a0.z + a1.z) + (a2.z + a3.z));
            r.w = 0.2f * self.w + 0.8f * ((a0.w + a1.w) + (a2.w + a3.w));
            storeh4(emb_out + (size_t)row * DIM + t * 4, r);
        }
    } else if (blockIdx.x < NBKT + S1_ACC_BLOCKS) {
        // acc0: store layer-0 contribution from the fp32 tables
        const int s = ((int)blockIdx.x - NBKT) * 16 + wid * 4 + g;   // < 8192
        const int node = (s < NB) ? users[s] : (NUM_USERS + items[s - NB]);
        const float* p = (node < NUM_USERS) ? ue + (size_t)node * DIM
                                            : ie + (size_t)(node - NUM_USERS) * DIM;
        *(float4*)(acc_small + (size_t)s * DIM + t * 4) = *(const float4*)(p + t * 4);
    } else if (blockIdx.x < NBKT + S1_ACC_BLOCKS + S1_EXP_BLOCKS) {
        int i = ((int)blockIdx.x - NBKT - S1_ACC_BLOCKS) * 256 + (int)threadIdx.x;
        const int stride = S1_EXP_BLOCKS * 256;
        for (; i < N_EDGES; i += stride)
            if (mask3[erow[i]]) mask2[ecol[i]] = 1;
    } else {
        int i = ((int)blockIdx.x - NBKT - S1_ACC_BLOCKS - S1_EXP_BLOCKS) * 256
                + (int)threadIdx.x;
        if (i < N_NODES && mask3[i]) mask2[i] = 1;
    }
}

// ---------------------------------------------------------------------------
// spmm2 (layer 2): global ELL, masked, fp16 gathers + acc1 ride-along
// ---------------------------------------------------------------------------
__global__ void spmm_kernel(const int* __restrict__ counts,
                            const int2* __restrict__ ell,
                            const __half* __restrict__ xsrc,
                            const unsigned char* __restrict__ mask,
                            const int* __restrict__ ovf_cnt,
                            const int4* __restrict__ ovf,
                            const int* __restrict__ users,
                            const int* __restrict__ items,
                            float* __restrict__ acc_small,
                            __half* __restrict__ xout) {
    const int wid  = threadIdx.x >> 6;
    const int lane = threadIdx.x & 63;
    const int g    = lane >> 4;
    const int t    = lane & 15;

    if (blockIdx.x < SPMM_BLOCKS) {
        const int row = blockIdx.x * 16 + wid * 4 + g;
        bool active = mask[row] != 0;
        int cnt = 0;
        if (active) {
            cnt = counts[row];
            cnt = cnt < ELL_W ? cnt : ELL_W;
        }
        const int2* ep = ell + (size_t)row * ELL_W;
        float4 a0 = {0,0,0,0}, a1 = {0,0,0,0}, a2 = {0,0,0,0}, a3 = {0,0,0,0};
        int j = 0;
        for (; j + 4 <= cnt; j += 4) {
            int4 cv0 = *(const int4*)(ep + j);
            int4 cv1 = *(const int4*)(ep + j + 2);
            float4 x0 = loadh4(xsrc + (size_t)cv0.x * DIM + t * 4);
            float4 x1 = loadh4(xsrc + (size_t)cv0.z * DIM + t * 4);
            float4 x2 = loadh4(xsrc + (size_t)cv1.x * DIM + t * 4);
            float4 x3 = loadh4(xsrc + (size_t)cv1.z * DIM + t * 4);
            a0 = f4fma(__int_as_float(cv0.y), x0, a0);
            a1 = f4fma(__int_as_float(cv0.w), x1, a1);
            a2 = f4fma(__int_as_float(cv1.y), x2, a2);
            a3 = f4fma(__int_as_float(cv1.w), x3, a3);
        }
        for (; j + 2 <= cnt; j += 2) {
            int4 cv = *(const int4*)(ep + j);
            float4 x0 = loadh4(xsrc + (size_t)cv.x * DIM + t * 4);
            float4 x1 = loadh4(xsrc + (size_t)cv.z * DIM + t * 4);
            a0 = f4fma(__int_as_float(cv.y), x0, a0);
            a1 = f4fma(__int_as_float(cv.w), x1, a1);
        }
        if (j < cnt) {
            int2 cv = ep[j];
            float4 xv = loadh4(xsrc + (size_t)cv.x * DIM + t * 4);
            a0 = f4fma(__int_as_float(cv.y), xv, a0);
        }
        int novf = *ovf_cnt;
        if (novf > 0) {
            novf = novf < OVF_CAP ? novf : OVF_CAP;
            for (int k = 0; k < novf; ++k) {
                int4 o = ovf[k];
                if (active && o.x == row) {
                    float4 xv = loadh4(xsrc + (size_t)o.y * DIM + t * 4);
                    a0 = f4fma(__int_as_float(o.z), xv, a0);
                }
            }
        }
        if (active) {
            float4 self = loadh4(xsrc + (size_t)row * DIM + t * 4);
            float4 r;
            r.x = 0.2f * self.x + 0.8f * ((a0.x + a1.x) + (a2.x + a3.x));
            r.y = 0.2f * self.y + 0.8f * ((a0.y + a1.y) + (a2.y + a3.y));
            r.z = 0.2f * self.z + 0.8f * ((a0.z + a1.z) + (a2.z + a3.z));
            r.w = 0.2f * self.w + 0.8f * ((a0.w + a1.w) + (a2.w + a3.w));
            storeh4(xout + (size_t)row * DIM + t * 4, r);
        }
    } else {
        // acc1 += e1 at sampled slots (xsrc = emb_a)
        const int s = (blockIdx.x - SPMM_BLOCKS) * 16 + wid * 4 + g;
        const int node = (s < NB) ? users[s] : (NUM_USERS + items[s - NB]);
        float4 v = loadh4(xsrc + (size_t)node * DIM + t * 4);
        float4* ap = (float4*)(acc_small + (size_t)s * DIM + t * 4);
        float4 a = *ap;
        a.x += v.x; a.y += v.y; a.z += v.z; a.w += v.w;
        *ap = a;
    }
}

// ---------------------------------------------------------------------------
// sp3: slot-form layer 3 — acc[slot] += e2(node) + e3(node)
//      e3 = 0.2*self + 0.8*sum, self = e2(node) from emb_b
// ---------------------------------------------------------------------------
__global__ void sp3_kernel(const int* __restrict__ counts,
                           const int2* __restrict__ ell,
                           const __half* __restrict__ emb2,
                           const int* __restrict__ ovf_cnt,
                           const int4* __restrict__ ovf,
                           const int* __restrict__ users,
                           const int* __restrict__ items,
                           float* __restrict__ acc_small) {
    const int wid  = threadIdx.x >> 6;
    const int lane = threadIdx.x & 63;
    const int g    = lane >> 4;
    const int t    = lane & 15;
    const int s = blockIdx.x * 16 + wid * 4 + g;          // < 8192
    if (s >= NSAMP) return;
    const int node = (s < NB) ? users[s] : (NUM_USERS + items[s - NB]);

    int cnt = counts[node];
    cnt = cnt < ELL_W ? cnt : ELL_W;
    const int2* ep = ell + (size_t)node * ELL_W;
    float4 a0 = {0,0,0,0}, a1 = {0,0,0,0}, a2 = {0,0,0,0}, a3 = {0,0,0,0};
    int j = 0;
    for (; j + 4 <= cnt; j += 4) {
        int4 cv0 = *(const int4*)(ep + j);
        int4 cv1 = *(const int4*)(ep + j + 2);
        float4 x0 = loadh4(emb2 + (size_t)cv0.x * DIM + t * 4);
        float4 x1 = loadh4(emb2 + (size_t)cv0.z * DIM + t * 4);
        float4 x2 = loadh4(emb2 + (size_t)cv1.x * DIM + t * 4);
        float4 x3 = loadh4(emb2 + (size_t)cv1.z * DIM + t * 4);
        a0 = f4fma(__int_as_float(cv0.y), x0, a0);
        a1 = f4fma(__int_as_float(cv0.w), x1, a1);
        a2 = f4fma(__int_as_float(cv1.y), x2, a2);
        a3 = f4fma(__int_as_float(cv1.w), x3, a3);
    }
    for (; j + 2 <= cnt; j += 2) {
        int4 cv = *(const int4*)(ep + j);
        float4 x0 = loadh4(emb2 + (size_t)cv.x * DIM + t * 4);
        float4 x1 = loadh4(emb2 + (size_t)cv.z * DIM + t * 4);
        a0 = f4fma(__int_as_float(cv.y), x0, a0);
        a1 = f4fma(__int_as_float(cv.w), x1, a1);
    }
    if (j < cnt) {
        int2 cv = ep[j];
        float4 xv = loadh4(emb2 + (size_t)cv.x * DIM + t * 4);
        a0 = f4fma(__int_as_float(cv.y), xv, a0);
    }
    int novf = *ovf_cnt;
    if (novf > 0) {
        novf = novf < OVF_CAP ? novf : OVF_CAP;
        for (int k = 0; k < novf; ++k) {
            int4 o = ovf[k];
            if (o.x == node) {
                float4 xv = loadh4(emb2 + (size_t)o.y * DIM + t * 4);
                a0 = f4fma(__int_as_float(o.z), xv, a0);
            }
        }
    }
    float4 self = loadh4(emb2 + (size_t)node * DIM + t * 4);
    float4* ap = (float4*)(acc_small + (size_t)s * DIM + t * 4);
    float4 a = *ap;
    // += e2 + e3 = self + (0.2*self + 0.8*sum) = 1.2*self + 0.8*sum
    a.x += 1.2f * self.x + 0.8f * ((a0.x + a1.x) + (a2.x + a3.x));
    a.y += 1.2f * self.y + 0.8f * ((a0.y + a1.y) + (a2.y + a3.y));
    a.z += 1.2f * self.z + 0.8f * ((a0.z + a1.z) + (a2.z + a3.z));
    a.w += 1.2f * self.w + 0.8f * ((a0.w + a1.w) + (a2.w + a3.w));
    *ap = a;
}

// ---------------------------------------------------------------------------
// out[b] = dot(acc[b], acc[NB+b]) / 16
// ---------------------------------------------------------------------------
__global__ void dot_kernel(const float* __restrict__ acc_small,
                           float* __restrict__ out) {
    int w = (blockIdx.x * blockDim.x + threadIdx.x) >> 6;
    int lane = threadIdx.x & 63;
    if (w >= NB) return;
    float p = acc_small[w * DIM + lane] * acc_small[(NB + w) * DIM + lane];
    #pragma unroll
    for (int o = 32; o > 0; o >>= 1) p += __shfl_down(p, o, 64);
    if (lane == 0) out[w] = p * (1.0f / 16.0f);
}

// ---------------------------------------------------------------------------
extern "C" void kernel_launch(void* const* d_in, const int* in_sizes, int n_in,
                              void* d_out, int out_size, void* d_ws, size_t ws_size,
                              hipStream_t stream) {
    const int*   users = (const int*)  d_in[0];
    const int*   items = (const int*)  d_in[1];
    const int*   erow  = (const int*)  d_in[2];
    const int*   ecol  = (const int*)  d_in[3];
    const float* evalv = (const float*)d_in[4];
    const float* ue    = (const float*)d_in[5];
    const float* ie    = (const float*)d_in[6];
    float* out = (float*)d_out;

    // workspace layout (~101 MB)
    __half* xh        = (__half*)d_ws;                      // 19.2 MB
    __half* emb_a     = xh + ND;                            // 19.2 MB
    __half* emb_b     = emb_a + ND;                         // 19.2 MB
    float*  acc_small = (float*)(emb_b + ND);               // 2 MB
    int2*   barr      = (int2*)(acc_small + NSAMP * DIM);   // 11.1 MB
    int2*   ell       = barr + (size_t)NBKT * BCAP;         // 28.9 MB
    int*    counts    = (int*)(ell + (size_t)NROWS_PAD * ELL_W); // 0.6 MB
    int*    gtails    = counts + NROWS_PAD;                 // NBKT
    int*    ovf_cnt   = gtails + NBKT;                      // 1
    int4*   ovf       = (int4*)(((uintptr_t)(ovf_cnt + 1) + 15) & ~(uintptr_t)15);
    unsigned char* mask3 = (unsigned char*)(ovf + OVF_CAP); // N_NODES
    unsigned char* mask2 = mask3 + N_NODES;                 // N_NODES

    // zero gtails | ovf_cnt | ovf | mask3 | mask2 (contiguous, ~310 KB)
    size_t zbytes = (size_t)((mask2 + N_NODES) - (unsigned char*)gtails);
    hipMemsetAsync(gtails, 0, zbytes, stream);

    k1_kernel<<<K1_EDGE_BLOCKS + K1_MARK_BLOCKS + K1_CVT_BLOCKS, K1_THREADS, 0, stream>>>(
        erow, ecol, evalv, users, items, ue, ie,
        gtails, barr, ovf, ovf_cnt, mask3, xh);

    // s1: ELL build + cnt-pruned writeout + layer-1 spmm + acc0 + expand + copy
    s1_kernel<<<NBKT + S1_ACC_BLOCKS + S1_EXP_BLOCKS + S1_CPY_BLOCKS, 256, 0, stream>>>(
        erow, ecol, gtails, barr, xh, ue, ie, counts, ell, ovf, ovf_cnt,
        mask3, mask2, users, items, acc_small, emb_a);

    // layer 2 (mask2) + acc1 (from emb_a)
    spmm_kernel<<<SPMM_BLOCKS + ACC_BLOCKS, 256, 0, stream>>>(
        counts, ell, emb_a, mask2, ovf_cnt, ovf,
        users, items, acc_small, emb_b);

    // layer 3 slot-form: acc += e2 + e3
    sp3_kernel<<<SP3_BLOCKS, 256, 0, stream>>>(
        counts, ell, emb_b, ovf_cnt, ovf, users, items, acc_small);

    // dot on acc only
    dot_kernel<<<(NB * 64 + 255) / 256, 256, 0, stream>>>(acc_small, out);
}

// Round 15
// 196.908 us; speedup vs baseline: 1.1328x; 1.0752x over previous
//
#include <hip/hip_runtime.h>
#include <hip/hip_fp16.h>
#include <stdint.h>
#include <string.h>

// LightGCN propagation — R14 structure with 512-thread s1.
//  K1: wide-block LDS-staged counting sort + mark + cvt ride-along.
//  s1: 512 threads/block (same 46KB LDS -> 3 blocks/CU but 24 waves/CU,
//      2x the latency hiding of R14's 256-thread version): ELL build in LDS
//      -> cnt-pruned writeout -> layer-1 spmm from LDS; acc0 + expand + copy
//      ride-alongs rescaled to 512 threads.
//  spmm2: global ELL (mask2 rows), fp16 gathers + acc1 ride-along.
//  sp3: slot-form layer 3 — acc += e2 + e3 at 8192 slots.
//  dot: batched dot on acc_small only.

#define NUM_USERS 100000
#define NUM_ITEMS 50000
#define N_NODES   150000
#define DIM       64
#define N_EDGES   1200000
#define ND        (N_NODES * DIM)
#define NB        4096
#define NSAMP     (2 * NB)

#define ELL_W     24
#define NBKT      640               // buckets
#define RPB       235               // rows per bucket (640*235 = 150400)
#define NROWS_PAD (NBKT * RPB)
#define BCAP      2176              // records per bucket array (mean 1875, +7s)
#define SCAP      11                // K1 LDS staging records per bucket
#define OVF_CAP   512

#define K1_THREADS     1024
#define K1_EDGE_BLOCKS 256
#define K1_ROUNDS      2
#define K1_MARK_BLOCKS 8            // 8*1024 = 8192 = NSAMP
#define K1_CVT_BLOCKS  128

#define S1_THREADS     512
#define S1_ACC_BLOCKS  256          // 32 slots/block * 256 = 8192
#define S1_EXP_BLOCKS  1024
#define S1_CPY_BLOCKS  293          // 293*512 >= N_NODES

#define SPMM_BLOCKS    9375         // 16 rows/block
#define ACC_BLOCKS     512          // 16 slots/block
#define SP3_BLOCKS     512          // 16 slots/block over 8192 slots

// ---- fp16 pack/unpack helpers (compute in fp32) ---------------------------
__device__ __forceinline__ int h2i(__half2 h) { int r; memcpy(&r, &h, 4); return r; }
__device__ __forceinline__ __half2 i2h(int i) { __half2 h; memcpy(&h, &i, 4); return h; }

__device__ __forceinline__ float4 loadh4(const __half* p) {
    int2 v = *(const int2*)p;
    float2 a = __half22float2(i2h(v.x));
    float2 b = __half22float2(i2h(v.y));
    return make_float4(a.x, a.y, b.x, b.y);
}
__device__ __forceinline__ void storeh4(__half* p, float4 v) {
    int2 o;
    o.x = h2i(__floats2half2_rn(v.x, v.y));
    o.y = h2i(__floats2half2_rn(v.z, v.w));
    *(int2*)p = o;
}
__device__ __forceinline__ float4 f4fma(float v, float4 x, float4 a) {
    a.x += v * x.x; a.y += v * x.y; a.z += v * x.z; a.w += v * x.w;
    return a;
}

// ---------------------------------------------------------------------------
// K1: LDS-staged counting sort (wide blocks) + mark + cvt ride-along [R11]
// ---------------------------------------------------------------------------
__global__ __launch_bounds__(K1_THREADS)
void k1_kernel(const int* __restrict__ erow,
               const int* __restrict__ ecol,
               const float* __restrict__ evalv,
               const int* __restrict__ users,
               const int* __restrict__ items,
               const float* __restrict__ ue,
               const float* __restrict__ ie,
               int* __restrict__ gtails,
               int2* __restrict__ barr,
               int4* __restrict__ ovf,
               int* __restrict__ ovf_cnt,
               unsigned char* __restrict__ mask3,
               __half* __restrict__ xh) {
    __shared__ int2 stage[NBKT * SCAP];   // 56.3 KB
    __shared__ int  scnt[NBKT];           // 2.5 KB
    if (blockIdx.x < K1_EDGE_BLOCKS) {
        for (int k = threadIdx.x; k < NBKT; k += K1_THREADS) scnt[k] = 0;
        __syncthreads();
        for (int rnd = 0; rnd < K1_ROUNDS; ++rnd) {
            int base = ((rnd * K1_EDGE_BLOCKS + (int)blockIdx.x) * K1_THREADS
                        + (int)threadIdx.x) * 4;
            if (base < N_EDGES) {
                int4   r4 = *(const int4*)(erow + base);
                int4   c4 = *(const int4*)(ecol + base);
                float4 v4 = *(const float4*)(evalv + base);
                int   rr[4] = {r4.x, r4.y, r4.z, r4.w};
                int   cc[4] = {c4.x, c4.y, c4.z, c4.w};
                float vv[4] = {v4.x, v4.y, v4.z, v4.w};
                #pragma unroll
                for (int u = 0; u < 4; ++u) {
                    int b    = rr[u] / RPB;
                    int rloc = rr[u] - b * RPB;
                    int2 rec = make_int2(cc[u] | (rloc << 18), __float_as_int(vv[u]));
                    int s = atomicAdd(&scnt[b], 1);
                    if (s < SCAP) {
                        stage[b * SCAP + s] = rec;
                    } else {
                        atomicSub(&scnt[b], 1);
                        int gp = atomicAdd(&gtails[b], 1);
                        if (gp < BCAP) barr[(size_t)b * BCAP + gp] = rec;
                        else { int q = atomicAdd(ovf_cnt, 1);
                               if (q < OVF_CAP)
                                   ovf[q] = make_int4(rr[u], cc[u], __float_as_int(vv[u]), 0); }
                    }
                }
            }
            __syncthreads();
            for (int b = threadIdx.x; b < NBKT; b += K1_THREADS) {
                int c = scnt[b];
                if (c >= 8) {
                    int gp = atomicAdd(&gtails[b], 8);
                    if (gp + 8 <= BCAP) {
                        int2* dst = barr + (size_t)b * BCAP + gp;
                        #pragma unroll
                        for (int i = 0; i < 8; ++i) dst[i] = stage[b * SCAP + i];
                    } else {
                        for (int i = 0; i < 8; ++i) {
                            int2 rc = stage[b * SCAP + i];
                            if (gp + i < BCAP) barr[(size_t)b * BCAP + gp + i] = rc;
                            else { int q = atomicAdd(ovf_cnt, 1);
                                   if (q < OVF_CAP)
                                       ovf[q] = make_int4(b * RPB + (rc.x >> 18),
                                                          rc.x & 0x3FFFF, rc.y, 0); }
                        }
                    }
                    c -= 8;
                    for (int i = 0; i < c; ++i)
                        stage[b * SCAP + i] = stage[b * SCAP + 8 + i];
                    scnt[b] = c;
                }
            }
            __syncthreads();
        }
        for (int b = threadIdx.x; b < NBKT; b += K1_THREADS) {
            int c = scnt[b];
            if (c > 0) {
                int gp = atomicAdd(&gtails[b], c);
                for (int i = 0; i < c; ++i) {
                    int2 rc = stage[b * SCAP + i];
                    if (gp + i < BCAP) barr[(size_t)b * BCAP + gp + i] = rc;
                    else { int q = atomicAdd(ovf_cnt, 1);
                           if (q < OVF_CAP)
                               ovf[q] = make_int4(b * RPB + (rc.x >> 18),
                                                  rc.x & 0x3FFFF, rc.y, 0); }
                }
            }
        }
    } else if (blockIdx.x < K1_EDGE_BLOCKS + K1_MARK_BLOCKS) {
        int i = ((int)blockIdx.x - K1_EDGE_BLOCKS) * K1_THREADS + (int)threadIdx.x;
        if (i < NB)         mask3[users[i]] = 1;
        else if (i < NSAMP) mask3[NUM_USERS + items[i - NB]] = 1;
    } else {
        const int n4  = ND / 4;
        const int nu4 = NUM_USERS * DIM / 4;
        int i = ((int)blockIdx.x - K1_EDGE_BLOCKS - K1_MARK_BLOCKS) * K1_THREADS
                + (int)threadIdx.x;
        const int stride = K1_CVT_BLOCKS * K1_THREADS;
        int2* xh4 = (int2*)xh;
        for (; i < n4; i += stride) {
            float4 v = (i < nu4) ? ((const float4*)ue)[i]
                                 : ((const float4*)ie)[i - nu4];
            int2 o;
            o.x = h2i(__floats2half2_rn(v.x, v.y));
            o.y = h2i(__floats2half2_rn(v.z, v.w));
            xh4[i] = o;
        }
    }
}

// ---------------------------------------------------------------------------
// s1 (512 threads): ELL build (LDS) + cnt-pruned writeout + layer-1 spmm
//     from LDS + acc0 + mask expand + mask copy ride-alongs
// ---------------------------------------------------------------------------
__global__ __launch_bounds__(S1_THREADS)
void s1_kernel(const int* __restrict__ erow,
               const int* __restrict__ ecol,
               const int* __restrict__ gtails,
               const int2* __restrict__ barr,
               const __half* __restrict__ xh,
               const float* __restrict__ ue,
               const float* __restrict__ ie,
               int* __restrict__ counts,
               int2* __restrict__ ell,
               int4* __restrict__ ovf,
               int* __restrict__ ovf_cnt,
               const unsigned char* __restrict__ mask3,
               unsigned char* __restrict__ mask2,
               const int* __restrict__ users,
               const int* __restrict__ items,
               float* __restrict__ acc_small,
               __half* __restrict__ emb_out) {
    __shared__ __align__(16) int2 lell[RPB * ELL_W];   // 45.1 KB
    __shared__ int lcnt[RPB];
    const int group = threadIdx.x >> 4;   // 0..31
    const int t     = threadIdx.x & 15;

    if (blockIdx.x < NBKT) {
        const int bkt   = blockIdx.x;
        const int rbase = bkt * RPB;
        // ---- phase 1: build LDS ELL from sorted records ----
        for (int k = threadIdx.x; k < RPB; k += S1_THREADS) lcnt[k] = 0;
        __syncthreads();
        int n = gtails[bkt];
        n = n < BCAP ? n : BCAP;
        for (int e = threadIdx.x; e < n; e += S1_THREADS) {
            int2 rec = barr[(size_t)bkt * BCAP + e];
            int col  = rec.x & 0x3FFFF;
            int rloc = rec.x >> 18;
            int slot = atomicAdd(&lcnt[rloc], 1);
            if (slot < ELL_W)
                lell[rloc * ELL_W + slot] = make_int2(col, rec.y);
            else { int q = atomicAdd(ovf_cnt, 1);
                   if (q < OVF_CAP) ovf[q] = make_int4(rbase + rloc, col, rec.y, 0); }
        }
        __syncthreads();
        // ---- phase 2: cnt-pruned writeout (rows are 192B line-aligned) ----
        {
            int4* g4 = (int4*)(ell + (size_t)rbase * ELL_W);
            const int4* l4 = (const int4*)lell;
            const int PPR = ELL_W / 2;   // 12 int4 pairs per row
            for (int idx = threadIdx.x; idx < RPB * PPR; idx += S1_THREADS) {
                int row = idx / PPR;
                int pr  = idx - row * PPR;
                int c = lcnt[row]; c = c < ELL_W ? c : ELL_W;
                if (pr * 2 < c) g4[idx] = l4[idx];
            }
            for (int k = threadIdx.x; k < RPB; k += S1_THREADS)
                counts[rbase + k] = lcnt[k];
        }
        // ---- phase 3: layer-1 spmm reading ELL from LDS ----
        int novf = *ovf_cnt;
        novf = novf < OVF_CAP ? novf : OVF_CAP;
        for (int k = 0; k < 8; ++k) {                 // 32 groups x 8 = 256 >= 235
            int rloc = group + 32 * k;
            if (rloc >= RPB) break;
            int row = rbase + rloc;
            if (row >= N_NODES) continue;
            int cnt = lcnt[rloc];
            cnt = cnt < ELL_W ? cnt : ELL_W;
            const int2* ep = &lell[rloc * ELL_W];
            float4 a0 = {0,0,0,0}, a1 = {0,0,0,0}, a2 = {0,0,0,0}, a3 = {0,0,0,0};
            int j = 0;
            for (; j + 4 <= cnt; j += 4) {
                int4 cv0 = *(const int4*)(ep + j);
                int4 cv1 = *(const int4*)(ep + j + 2);
                float4 x0 = loadh4(xh + (size_t)cv0.x * DIM + t * 4);
                float4 x1 = loadh4(xh + (size_t)cv0.z * DIM + t * 4);
                float4 x2 = loadh4(xh + (size_t)cv1.x * DIM + t * 4);
                float4 x3 = loadh4(xh + (size_t)cv1.z * DIM + t * 4);
                a0 = f4fma(__int_as_float(cv0.y), x0, a0);
                a1 = f4fma(__int_as_float(cv0.w), x1, a1);
                a2 = f4fma(__int_as_float(cv1.y), x2, a2);
                a3 = f4fma(__int_as_float(cv1.w), x3, a3);
            }
            for (; j + 2 <= cnt; j += 2) {
                int4 cv = *(const int4*)(ep + j);
                float4 x0 = loadh4(xh + (size_t)cv.x * DIM + t * 4);
                float4 x1 = loadh4(xh + (size_t)cv.z * DIM + t * 4);
                a0 = f4fma(__int_as_float(cv.y), x0, a0);
                a1 = f4fma(__int_as_float(cv.w), x1, a1);
            }
            if (j < cnt) {
                int2 cv = ep[j];
                float4 xv = loadh4(xh + (size_t)cv.x * DIM + t * 4);
                a0 = f4fma(__int_as_float(cv.y), xv, a0);
            }
            for (int q = 0; q < novf; ++q) {
                int4 o = ovf[q];
                if (o.x == row) {
                    float4 xv = loadh4(xh + (size_t)o.y * DIM + t * 4);
                    a0 = f4fma(__int_as_float(o.z), xv, a0);
                }
            }
            float4 self = loadh4(xh + (size_t)row * DIM + t * 4);
            float4 r;
            r.x = 0.2f * self.x + 0.8f * ((a0.x + a1.x) + (a2.x + a3.x));
            r.y = 0.2f * self.y + 0.8f * ((a0.y + a1.y) + (a2.y + a3.y));
            r.z = 0.2f * self.z + 0.8f * ((a0.z + a1.z) + (a2.z + a3.z));
            r.w = 0.2f * self.w + 0.8f * ((a0.w + a1.w) + (a2.w + a3.w));
            storeh4(emb_out + (size_t)row * DIM + t * 4, r);
        }
    } else if (blockIdx.x < NBKT + S1_ACC_BLOCKS) {
        // acc0: store layer-0 contribution from the fp32 tables (32 slots/blk)
        const int s = ((int)blockIdx.x - NBKT) * 32 + group;   // < 8192
        const int node = (s < NB) ? users[s] : (NUM_USERS + items[s - NB]);
        const float* p = (node < NUM_USERS) ? ue + (size_t)node * DIM
                                            : ie + (size_t)(node - NUM_USERS) * DIM;
        *(float4*)(acc_small + (size_t)s * DIM + t * 4) = *(const float4*)(p + t * 4);
    } else if (blockIdx.x < NBKT + S1_ACC_BLOCKS + S1_EXP_BLOCKS) {
        int i = ((int)blockIdx.x - NBKT - S1_ACC_BLOCKS) * S1_THREADS
                + (int)threadIdx.x;
        const int stride = S1_EXP_BLOCKS * S1_THREADS;
        for (; i < N_EDGES; i += stride)
            if (mask3[erow[i]]) mask2[ecol[i]] = 1;
    } else {
        int i = ((int)blockIdx.x - NBKT - S1_ACC_BLOCKS - S1_EXP_BLOCKS) * S1_THREADS
                + (int)threadIdx.x;
        if (i < N_NODES && mask3[i]) mask2[i] = 1;
    }
}

// ---------------------------------------------------------------------------
// spmm2 (layer 2): global ELL, masked, fp16 gathers + acc1 ride-along
// ---------------------------------------------------------------------------
__global__ void spmm_kernel(const int* __restrict__ counts,
                            const int2* __restrict__ ell,
                            const __half* __restrict__ xsrc,
                            const unsigned char* __restrict__ mask,
                            const int* __restrict__ ovf_cnt,
                            const int4* __restrict__ ovf,
                            const int* __restrict__ users,
                            const int* __restrict__ items,
                            float* __restrict__ acc_small,
                            __half* __restrict__ xout) {
    const int wid  = threadIdx.x >> 6;
    const int lane = threadIdx.x & 63;
    const int g    = lane >> 4;
    const int t    = lane & 15;

    if (blockIdx.x < SPMM_BLOCKS) {
        const int row = blockIdx.x * 16 + wid * 4 + g;
        bool active = mask[row] != 0;
        int cnt = 0;
        if (active) {
            cnt = counts[row];
            cnt = cnt < ELL_W ? cnt : ELL_W;
        }
        const int2* ep = ell + (size_t)row * ELL_W;
        float4 a0 = {0,0,0,0}, a1 = {0,0,0,0}, a2 = {0,0,0,0}, a3 = {0,0,0,0};
        int j = 0;
        for (; j + 4 <= cnt; j += 4) {
            int4 cv0 = *(const int4*)(ep + j);
            int4 cv1 = *(const int4*)(ep + j + 2);
            float4 x0 = loadh4(xsrc + (size_t)cv0.x * DIM + t * 4);
            float4 x1 = loadh4(xsrc + (size_t)cv0.z * DIM + t * 4);
            float4 x2 = loadh4(xsrc + (size_t)cv1.x * DIM + t * 4);
            float4 x3 = loadh4(xsrc + (size_t)cv1.z * DIM + t * 4);
            a0 = f4fma(__int_as_float(cv0.y), x0, a0);
            a1 = f4fma(__int_as_float(cv0.w), x1, a1);
            a2 = f4fma(__int_as_float(cv1.y), x2, a2);
            a3 = f4fma(__int_as_float(cv1.w), x3, a3);
        }
        for (; j + 2 <= cnt; j += 2) {
            int4 cv = *(const int4*)(ep + j);
            float4 x0 = loadh4(xsrc + (size_t)cv.x * DIM + t * 4);
            float4 x1 = loadh4(xsrc + (size_t)cv.z * DIM + t * 4);
            a0 = f4fma(__int_as_float(cv.y), x0, a0);
            a1 = f4fma(__int_as_float(cv.w), x1, a1);
        }
        if (j < cnt) {
            int2 cv = ep[j];
            float4 xv = loadh4(xsrc + (size_t)cv.x * DIM + t * 4);
            a0 = f4fma(__int_as_float(cv.y), xv, a0);
        }
        int novf = *ovf_cnt;
        if (novf > 0) {
            novf = novf < OVF_CAP ? novf : OVF_CAP;
            for (int k = 0; k < novf; ++k) {
                int4 o = ovf[k];
                if (active && o.x == row) {
                    float4 xv = loadh4(xsrc + (size_t)o.y * DIM + t * 4);
                    a0 = f4fma(__int_as_float(o.z), xv, a0);
                }
            }
        }
        if (active) {
            float4 self = loadh4(xsrc + (size_t)row * DIM + t * 4);
            float4 r;
            r.x = 0.2f * self.x + 0.8f * ((a0.x + a1.x) + (a2.x + a3.x));
            r.y = 0.2f * self.y + 0.8f * ((a0.y + a1.y) + (a2.y + a3.y));
            r.z = 0.2f * self.z + 0.8f * ((a0.z + a1.z) + (a2.z + a3.z));
            r.w = 0.2f * self.w + 0.8f * ((a0.w + a1.w) + (a2.w + a3.w));
            storeh4(xout + (size_t)row * DIM + t * 4, r);
        }
    } else {
        // acc1 += e1 at sampled slots (xsrc = emb_a)
        const int s = (blockIdx.x - SPMM_BLOCKS) * 16 + wid * 4 + g;
        const int node = (s < NB) ? users[s] : (NUM_USERS + items[s - NB]);
        float4 v = loadh4(xsrc + (size_t)node * DIM + t * 4);
        float4* ap = (float4*)(acc_small + (size_t)s * DIM + t * 4);
        float4 a = *ap;
        a.x += v.x; a.y += v.y; a.z += v.z; a.w += v.w;
        *ap = a;
    }
}

// ---------------------------------------------------------------------------
// sp3: slot-form layer 3 — acc[slot] += e2(node) + e3(node)
// ---------------------------------------------------------------------------
__global__ void sp3_kernel(const int* __restrict__ counts,
                           const int2* __restrict__ ell,
                           const __half* __restrict__ emb2,
                           const int* __restrict__ ovf_cnt,
                           const int4* __restrict__ ovf,
                           const int* __restrict__ users,
                           const int* __restrict__ items,
                           float* __restrict__ acc_small) {
    const int wid  = threadIdx.x >> 6;
    const int lane = threadIdx.x & 63;
    const int g    = lane >> 4;
    const int t    = lane & 15;
    const int s = blockIdx.x * 16 + wid * 4 + g;          // < 8192
    if (s >= NSAMP) return;
    const int node = (s < NB) ? users[s] : (NUM_USERS + items[s - NB]);

    int cnt = counts[node];
    cnt = cnt < ELL_W ? cnt : ELL_W;
    const int2* ep = ell + (size_t)node * ELL_W;
    float4 a0 = {0,0,0,0}, a1 = {0,0,0,0}, a2 = {0,0,0,0}, a3 = {0,0,0,0};
    int j = 0;
    for (; j + 4 <= cnt; j += 4) {
        int4 cv0 = *(const int4*)(ep + j);
        int4 cv1 = *(const int4*)(ep + j + 2);
        float4 x0 = loadh4(emb2 + (size_t)cv0.x * DIM + t * 4);
        float4 x1 = loadh4(emb2 + (size_t)cv0.z * DIM + t * 4);
        float4 x2 = loadh4(emb2 + (size_t)cv1.x * DIM + t * 4);
        float4 x3 = loadh4(emb2 + (size_t)cv1.z * DIM + t * 4);
        a0 = f4fma(__int_as_float(cv0.y), x0, a0);
        a1 = f4fma(__int_as_float(cv0.w), x1, a1);
        a2 = f4fma(__int_as_float(cv1.y), x2, a2);
        a3 = f4fma(__int_as_float(cv1.w), x3, a3);
    }
    for (; j + 2 <= cnt; j += 2) {
        int4 cv = *(const int4*)(ep + j);
        float4 x0 = loadh4(emb2 + (size_t)cv.x * DIM + t * 4);
        float4 x1 = loadh4(emb2 + (size_t)cv.z * DIM + t * 4);
        a0 = f4fma(__int_as_float(cv.y), x0, a0);
        a1 = f4fma(__int_as_float(cv.w), x1, a1);
    }
    if (j < cnt) {
        int2 cv = ep[j];
        float4 xv = loadh4(emb2 + (size_t)cv.x * DIM + t * 4);
        a0 = f4fma(__int_as_float(cv.y), xv, a0);
    }
    int novf = *ovf_cnt;
    if (novf > 0) {
        novf = novf < OVF_CAP ? novf : OVF_CAP;
        for (int k = 0; k < novf; ++k) {
            int4 o = ovf[k];
            if (o.x == node) {
                float4 xv = loadh4(emb2 + (size_t)o.y * DIM + t * 4);
                a0 = f4fma(__int_as_float(o.z), xv, a0);
            }
        }
    }
    float4 self = loadh4(emb2 + (size_t)node * DIM + t * 4);
    float4* ap = (float4*)(acc_small + (size_t)s * DIM + t * 4);
    float4 a = *ap;
    a.x += 1.2f * self.x + 0.8f * ((a0.x + a1.x) + (a2.x + a3.x));
    a.y += 1.2f * self.y + 0.8f * ((a0.y + a1.y) + (a2.y + a3.y));
    a.z += 1.2f * self.z + 0.8f * ((a0.z + a1.z) + (a2.z + a3.z));
    a.w += 1.2f * self.w + 0.8f * ((a0.w + a1.w) + (a2.w + a3.w));
    *ap = a;
}

// ---------------------------------------------------------------------------
__global__ void dot_kernel(const float* __restrict__ acc_small,
                           float* __restrict__ out) {
    int w = (blockIdx.x * blockDim.x + threadIdx.x) >> 6;
    int lane = threadIdx.x & 63;
    if (w >= NB) return;
    float p = acc_small[w * DIM + lane] * acc_small[(NB + w) * DIM + lane];
    #pragma unroll
    for (int o = 32; o > 0; o >>= 1) p += __shfl_down(p, o, 64);
    if (lane == 0) out[w] = p * (1.0f / 16.0f);
}

// ---------------------------------------------------------------------------
extern "C" void kernel_launch(void* const* d_in, const int* in_sizes, int n_in,
                              void* d_out, int out_size, void* d_ws, size_t ws_size,
                              hipStream_t stream) {
    const int*   users = (const int*)  d_in[0];
    const int*   items = (const int*)  d_in[1];
    const int*   erow  = (const int*)  d_in[2];
    const int*   ecol  = (const int*)  d_in[3];
    const float* evalv = (const float*)d_in[4];
    const float* ue    = (const float*)d_in[5];
    const float* ie    = (const float*)d_in[6];
    float* out = (float*)d_out;

    // workspace layout (~101 MB)
    __half* xh        = (__half*)d_ws;                      // 19.2 MB
    __half* emb_a     = xh + ND;                            // 19.2 MB
    __half* emb_b     = emb_a + ND;                         // 19.2 MB
    float*  acc_small = (float*)(emb_b + ND);               // 2 MB
    int2*   barr      = (int2*)(acc_small + NSAMP * DIM);   // 11.1 MB
    int2*   ell       = barr + (size_t)NBKT * BCAP;         // 28.9 MB
    int*    counts    = (int*)(ell + (size_t)NROWS_PAD * ELL_W); // 0.6 MB
    int*    gtails    = counts + NROWS_PAD;                 // NBKT
    int*    ovf_cnt   = gtails + NBKT;                      // 1
    int4*   ovf       = (int4*)(((uintptr_t)(ovf_cnt + 1) + 15) & ~(uintptr_t)15);
    unsigned char* mask3 = (unsigned char*)(ovf + OVF_CAP); // N_NODES
    unsigned char* mask2 = mask3 + N_NODES;                 // N_NODES

    // zero gtails | ovf_cnt | ovf | mask3 | mask2 (contiguous, ~310 KB)
    size_t zbytes = (size_t)((mask2 + N_NODES) - (unsigned char*)gtails);
    hipMemsetAsync(gtails, 0, zbytes, stream);

    k1_kernel<<<K1_EDGE_BLOCKS + K1_MARK_BLOCKS + K1_CVT_BLOCKS, K1_THREADS, 0, stream>>>(
        erow, ecol, evalv, users, items, ue, ie,
        gtails, barr, ovf, ovf_cnt, mask3, xh);

    // s1: ELL build + pruned writeout + layer-1 spmm + acc0 + expand + copy
    s1_kernel<<<NBKT + S1_ACC_BLOCKS + S1_EXP_BLOCKS + S1_CPY_BLOCKS, S1_THREADS, 0, stream>>>(
        erow, ecol, gtails, barr, xh, ue, ie, counts, ell, ovf, ovf_cnt,
        mask3, mask2, users, items, acc_small, emb_a);

    // layer 2 (mask2) + acc1 (from emb_a)
    spmm_kernel<<<SPMM_BLOCKS + ACC_BLOCKS, 256, 0, stream>>>(
        counts, ell, emb_a, mask2, ovf_cnt, ovf,
        users, items, acc_small, emb_b);

    // layer 3 slot-form: acc += e2 + e3
    sp3_kernel<<<SP3_BLOCKS, 256, 0, stream>>>(
        counts, ell, emb_b, ovf_cnt, ovf, users, items, acc_small);

    // dot on acc only
    dot_kernel<<<(NB * 64 + 255) / 256, 256, 0, stream>>>(acc_small, out);
}